// Round 15
// baseline (261.967 us; speedup 1.0000x reference)
//
#include <hip/hip_runtime.h>

// FGKAN scoring kernel for MI355X (gfx950).
//
// Restructure: x@W1 = h_set@W1_top + path@W1_bot.
//   tab = [entB|PentB] bf16 256B rows; relB bf16 (rows 0..31 = Prel1,
//   rows 32..1055+32 = Prel2[r0*32+r1]).
//
// R12 post-mortem: inst-count cut bought 65->61us only; VALUBusy ~82%.
// Missing from the model: 1/(1+e) is a full IEEE divide without fast-math
// (~8-10 VALU ops incl. 2 quarter-rate) x ~80 sigmoids/thread.
// R13: (1) k_main: sigmoid via v_rcp_f32 approx (__builtin_amdgcn_rcpf),
// also for 1/s0,1/s1 and final score; otherwise byte-identical to R12.
// (2) k_proj_ent: 128 rows/block (8 rows x float4 per thread) -> half the
// blocks, 2x sW amortization, -25% LDS reads per output.
// R13 -> R15: identical resubmit x2 (R13/R14 died to GPU acquisition
// timeouts; the rcp-sigmoid A/B vs R12's 61us k_main is still pending).
//
// d_ws layout: relB (1056*64 bf16 = 132KB) | tab (NE x 128 bf16 = 25.6MB)

#define NE   100000
#define NR   32
#define DIMD 64
#define BB   4096
#define TT   32
#define BT   (BB * TT)

__device__ __forceinline__ float rcpf(float x) { return __builtin_amdgcn_rcpf(x); }
__device__ __forceinline__ float sigf(float x) {
    return rcpf(1.0f + __expf(-x));   // v_mul+v_exp+v_add+v_rcp (no IEEE div)
}
__device__ __forceinline__ float4 ld4(const float* p) {
    return *reinterpret_cast<const float4*>(p);
}

// bf16 helpers
__device__ __forceinline__ unsigned short f2b(float x) {
    unsigned b = __builtin_bit_cast(unsigned, x);
    b += 0x7FFF + ((b >> 16) & 1);
    return (unsigned short)(b >> 16);
}
__device__ __forceinline__ float blo(unsigned u) {
    return __builtin_bit_cast(float, u << 16);
}
__device__ __forceinline__ float bhi(unsigned u) {
    return __builtin_bit_cast(float, u & 0xFFFF0000u);
}
__device__ __forceinline__ void unp8(uint4 v, float* f) {
    f[0] = blo(v.x); f[1] = bhi(v.x);
    f[2] = blo(v.y); f[3] = bhi(v.y);
    f[4] = blo(v.z); f[5] = bhi(v.z);
    f[6] = blo(v.w); f[7] = bhi(v.w);
}
__device__ __forceinline__ uint4 ldu4(const unsigned* p) {
    return *reinterpret_cast<const uint4*>(p);
}

__device__ __forceinline__ float reduce8(float x) {
    x += __shfl_xor(x, 1, 64);
    x += __shfl_xor(x, 2, 64);
    x += __shfl_xor(x, 4, 64);
    return x;
}

// ---------------------------------------------------------------- precompute
// tab row r (256B) = [ entB: 64 bf16 | PentB: 64 bf16 ], Pent = ent @ W1_top.
// 128 rows/block, 256 threads: thread (q=tid&15 dim-chunk, trow=tid>>4) owns
// rows 8*trow..8*trow+7, dims 4q..4q+3.
__global__ __launch_bounds__(256) void k_proj_ent(const float* __restrict__ ent,
                                                  const float* __restrict__ W1,
                                                  unsigned short* __restrict__ tab) {
    __shared__ float sW[64][68];
    __shared__ float sR[128][68];
    const int tid = threadIdx.x;
    const int row0 = blockIdx.x * 128;

    // stage W1 top half (64x64)
#pragma unroll
    for (int i = 0; i < 4; ++i) {
        const int idx = tid + 256 * i;        // 0..1023
        const int r = idx >> 4;
        const int c = idx & 15;
        const float4 wv = ld4(W1 + r * DIMD + 4 * c);
        sW[r][4 * c + 0] = wv.x; sW[r][4 * c + 1] = wv.y;
        sW[r][4 * c + 2] = wv.z; sW[r][4 * c + 3] = wv.w;
    }
    // stage 128 ent rows
#pragma unroll
    for (int i = 0; i < 8; ++i) {
        const int idx = tid + 256 * i;        // 0..2047
        const int r = idx >> 4;
        const int c = idx & 15;
        const int er = (row0 + r < NE) ? (row0 + r) : (NE - 1);
        const float4 rv = ld4(ent + er * DIMD + 4 * c);
        sR[r][4 * c + 0] = rv.x; sR[r][4 * c + 1] = rv.y;
        sR[r][4 * c + 2] = rv.z; sR[r][4 * c + 3] = rv.w;
    }
    __syncthreads();

    const int q = tid & 15;
    const int trow = tid >> 4;    // 0..15 -> rows 8*trow..8*trow+7
    float4 acc[8];
#pragma unroll
    for (int i = 0; i < 8; ++i) acc[i] = make_float4(0.f, 0.f, 0.f, 0.f);

#pragma unroll
    for (int kk = 0; kk < 16; ++kk) {
        float4 rr[8];
#pragma unroll
        for (int i = 0; i < 8; ++i) rr[i] = ld4(&sR[8 * trow + i][4 * kk]);
#pragma unroll
        for (int j = 0; j < 4; ++j) {
            const float4 wv = ld4(&sW[4 * kk + j][4 * q]);
#pragma unroll
            for (int i = 0; i < 8; ++i) {
                const float s = (j == 0) ? rr[i].x : (j == 1) ? rr[i].y
                              : (j == 2) ? rr[i].z : rr[i].w;
                acc[i].x = fmaf(s, wv.x, acc[i].x);
                acc[i].y = fmaf(s, wv.y, acc[i].y);
                acc[i].z = fmaf(s, wv.z, acc[i].z);
                acc[i].w = fmaf(s, wv.w, acc[i].w);
            }
        }
    }

    const int orow = row0 + 8 * trow;
#pragma unroll
    for (int i = 0; i < 8; ++i) {
        if (orow + i < NE) {
            unsigned short* rowp = tab + ((size_t)(orow + i) << 7);
            ushort4 ev, pv;
            ev.x = f2b(sR[8 * trow + i][4 * q + 0]);
            ev.y = f2b(sR[8 * trow + i][4 * q + 1]);
            ev.z = f2b(sR[8 * trow + i][4 * q + 2]);
            ev.w = f2b(sR[8 * trow + i][4 * q + 3]);
            pv.x = f2b(acc[i].x); pv.y = f2b(acc[i].y);
            pv.z = f2b(acc[i].z); pv.w = f2b(acc[i].w);
            *reinterpret_cast<ushort4*>(rowp + 4 * q) = ev;
            *reinterpret_cast<ushort4*>(rowp + 64 + 4 * q) = pv;
        }
    }
}

// relB rows: [0,32) = rel[r] @ W1_bot ; [32,1056): (rel[r0]*rel[r1]) @ W1_bot
__global__ __launch_bounds__(256) void k_proj_rel(const float* __restrict__ rel,
                                                  const float* __restrict__ W1,
                                                  unsigned short* __restrict__ relB) {
    int gid = blockIdx.x * 256 + threadIdx.x;
    int row = gid >> 6;
    int d = gid & 63;
    if (row < 32) {
        const float* a = rel + row * DIMD;
        float acc = 0.0f;
#pragma unroll
        for (int k = 0; k < DIMD; ++k)
            acc = fmaf(a[k], W1[(DIMD + k) * DIMD + d], acc);
        relB[row * DIMD + d] = f2b(acc);
    } else if (row < 32 + 1024) {
        const int rr = row - 32;
        const float* a = rel + (rr >> 5) * DIMD;
        const float* c = rel + (rr & 31) * DIMD;
        float acc = 0.0f;
#pragma unroll
        for (int k = 0; k < DIMD; ++k)
            acc = fmaf(a[k] * c[k], W1[(DIMD + k) * DIMD + d], acc);
        relB[row * DIMD + d] = f2b(acc);
    }
}

// ---------------------------------------------------------------- main
// One block per b. Wave w = branch. Lane = (g = t-subgroup in [0,8),
// q = 16B dim-chunk in [0,8)). p in [0,4): t = 8p + g.
__global__ __launch_bounds__(256) void k_main(
    const int* __restrict__ items,
    const int* __restrict__ uh, const int* __restrict__ ur, const int* __restrict__ ut,
    const int* __restrict__ ih, const int* __restrict__ ir, const int* __restrict__ itp,
    const int* __restrict__ ph, const int* __restrict__ pr, const int* __restrict__ pt,
    const int* __restrict__ oh, const int* __restrict__ orr, const int* __restrict__ ot,
    const unsigned short* __restrict__ tab,
    const unsigned short* __restrict__ relB,
    const float* __restrict__ W2,
    float* __restrict__ out) {
    const int b = blockIdx.x;
    const int tid = threadIdx.x;
    const int w = tid >> 6;
    const int lane = tid & 63;
    const int g = lane >> 3;   // t-subgroup [0,8)
    const int q = lane & 7;    // dim chunk [0,8)

    const int* hp;
    const int* rp;
    const int* tp;
    switch (w) {
        case 0: hp = uh; rp = ur; tp = ut; break;
        case 1: hp = ih; rp = ir; tp = itp; break;
        case 2: hp = ph; rp = pr; tp = pt; break;
        default: hp = oh; rp = orr; tp = ot; break;
    }

    __shared__ int sidx[4][3][2][TT];
    {
        const int l = lane >> 5;
        const int t0 = lane & 31;
        const int off = l * BT + b * TT + t0;
        sidx[w][0][l][t0] = hp[off];
        sidx[w][1][l][t0] = rp[off];
        sidx[w][2][l][t0] = tp[off];
    }
    const int item_idx = (w == 1) ? items[b] : 0;

    int jh0[4], jh1[4], jr0[4], jr1[4], jt0[4], jt1[4];
#pragma unroll
    for (int p = 0; p < 4; ++p) {
        const int t = 8 * p + g;
        jh0[p] = sidx[w][0][0][t];
        jh1[p] = sidx[w][0][1][t];
        jr0[p] = sidx[w][1][0][t];
        jr1[p] = sidx[w][1][1][t];
        jt0[p] = sidx[w][2][0][t];
        jt1[p] = sidx[w][2][1][t];
    }

    const unsigned* tabU = (const unsigned*)tab;   // row = 64 uints
    const unsigned* relU = (const unsigned*)relB;  // row = 32 uints

    // ---- batched Phase-A gathers (20 dwordx4 loads)
    uint4 rH[4], rA0[4], rA1[4], rR0[4], rR2[4];
#pragma unroll
    for (int p = 0; p < 4; ++p) {
        const unsigned* r0p = tabU + ((size_t)jh0[p] << 6) + 4 * q;
        rH[p] = ldu4(r0p);
        rA0[p] = ldu4(r0p + 32);
        rA1[p] = ldu4(tabU + ((size_t)jh1[p] << 6) + 32 + 4 * q);
        rR0[p] = ldu4(relU + ((size_t)jr0[p] << 5) + 4 * q);
        rR2[p] = ldu4(relU + ((size_t)(32 + jr0[p] * 32 + jr1[p]) << 5) + 4 * q);
    }

    float w2e[8];
    {
        const float4 wa = ld4(W2 + 8 * q);
        const float4 wb = ld4(W2 + 8 * q + 4);
        w2e[0] = wa.x; w2e[1] = wa.y; w2e[2] = wa.z; w2e[3] = wa.w;
        w2e[4] = wb.x; w2e[5] = wb.y; w2e[6] = wb.z; w2e[7] = wb.w;
    }

    // ---- Phase A compute
    float d0[4], d1[4];
    float aH[8] = {0.f, 0.f, 0.f, 0.f, 0.f, 0.f, 0.f, 0.f};
#pragma unroll
    for (int p = 0; p < 4; ++p) {
        float He[8], A0e[8], A1e[8], R0e[8], R2e[8];
        unp8(rH[p], He);
        unp8(rA0[p], A0e);
        unp8(rA1[p], A1e);
        unp8(rR0[p], R0e);
        unp8(rR2[p], R2e);
        float v = 0.f, u = 0.f;
#pragma unroll
        for (int j = 0; j < 8; ++j) {
            aH[j] += He[j];
            v = fmaf(sigf(A0e[j] + R0e[j]), w2e[j], v);
            u = fmaf(sigf(A0e[j] + A1e[j] + R2e[j]), w2e[j], u);
        }
        d0[p] = v;
        d1[p] = u;
    }

    // ---- issue Phase-C gathers; latency hides under Phase B
    uint4 rT0[4], rT1[4];
#pragma unroll
    for (int p = 0; p < 4; ++p) {
        rT0[p] = ldu4(tabU + ((size_t)jt0[p] << 6) + 4 * q);
        rT1[p] = ldu4(tabU + ((size_t)jt1[p] << 6) + 4 * q);
    }
    const uint4 rIt = ldu4(tabU + ((size_t)item_idx << 6) + 4 * q);

    // ---- Phase B: 8-lane reduces; e = exp(sigmoid(dot)); deferred norm
    float e0[4], e1[4];
    float s0 = 0.f, s1 = 0.f;
#pragma unroll
    for (int p = 0; p < 4; ++p) {
        e0[p] = __expf(sigf(reduce8(d0[p])));
        e1[p] = __expf(sigf(reduce8(d1[p])));
        s0 += e0[p];
        s1 += e1[p];
    }
    s0 += __shfl_xor(s0, 8, 64);
    s0 += __shfl_xor(s0, 16, 64);
    s0 += __shfl_xor(s0, 32, 64);
    s1 += __shfl_xor(s1, 8, 64);
    s1 += __shfl_xor(s1, 16, 64);
    s1 += __shfl_xor(s1, 32, 64);

    // ---- Phase C: unnormalized weighted t-emb sums (entB halves)
    float acc0[8] = {0.f, 0.f, 0.f, 0.f, 0.f, 0.f, 0.f, 0.f};
    float acc1[8] = {0.f, 0.f, 0.f, 0.f, 0.f, 0.f, 0.f, 0.f};
#pragma unroll
    for (int p = 0; p < 4; ++p) {
        float T0e[8], T1e[8];
        unp8(rT0[p], T0e);
        unp8(rT1[p], T1e);
#pragma unroll
        for (int j = 0; j < 8; ++j) {
            acc0[j] = fmaf(e0[p], T0e[j], acc0[j]);
            acc1[j] = fmaf(e1[p], T1e[j], acc1[j]);
        }
    }

    const float inv0 = rcpf(s0);
    const float inv1 = rcpf(s1);
    float ve[8];
#pragma unroll
    for (int j = 0; j < 8; ++j) {
        ve[j] = fmaf(acc0[j], inv0, fmaf(acc1[j], inv1, 0.03125f * aH[j]));
        ve[j] += __shfl_xor(ve[j], 8, 64);
        ve[j] += __shfl_xor(ve[j], 16, 64);
        ve[j] += __shfl_xor(ve[j], 32, 64);
    }

    if (w == 1) {  // item branch additionally adds ent[items[b]] (entB half)
        float Ie[8];
        unp8(rIt, Ie);
#pragma unroll
        for (int j = 0; j < 8; ++j) ve[j] += Ie[j];
    }

    __shared__ float vec[4][DIMD];
    if (g == 0) {
#pragma unroll
        for (int j = 0; j < 8; ++j) vec[w][8 * q + j] = ve[j];
    }
    __syncthreads();

    // score = sigmoid( sum_d e_u*e_p_i + e_p_u*e_i )
    if (tid < 64) {
        float z = fmaf(vec[0][tid], vec[3][tid], vec[2][tid] * vec[1][tid]);
#pragma unroll
        for (int m = 1; m < 64; m <<= 1) z += __shfl_xor(z, m, 64);
        if (tid == 0) out[b] = sigf(z);
    }
    if (b == 0 && tid == 0) out[BB] = 0.0f;  // kge_loss
}

extern "C" void kernel_launch(void* const* d_in, const int* in_sizes, int n_in,
                              void* d_out, int out_size, void* d_ws, size_t ws_size,
                              hipStream_t stream) {
    const int* items = (const int*)d_in[0];
    const int* uh = (const int*)d_in[1];
    const int* ur = (const int*)d_in[2];
    const int* ut = (const int*)d_in[3];
    const int* ih = (const int*)d_in[4];
    const int* ir = (const int*)d_in[5];
    const int* itp = (const int*)d_in[6];
    const int* ph = (const int*)d_in[7];
    const int* pr = (const int*)d_in[8];
    const int* pt = (const int*)d_in[9];
    const int* oh = (const int*)d_in[10];
    const int* orr = (const int*)d_in[11];
    const int* ot = (const int*)d_in[12];
    const float* ent = (const float*)d_in[13];
    const float* rel = (const float*)d_in[14];
    const float* W1 = (const float*)d_in[15];
    const float* W2 = (const float*)d_in[16];
    float* out = (float*)d_out;

    unsigned short* relB = (unsigned short*)d_ws;    // 1056 rows x 64 bf16 = 132KB
    unsigned short* tab = relB + 1056 * DIMD;        // NE x 128 bf16 = 25.6MB

    hipLaunchKernelGGL(k_proj_ent, dim3((NE + 127) / 128), dim3(256), 0, stream,
                       ent, W1, tab);
    hipLaunchKernelGGL(k_proj_rel, dim3((1056 * 64 + 255) / 256), dim3(256), 0,
                       stream, rel, W1, relB);
    hipLaunchKernelGGL(k_main, dim3(BB), dim3(256), 0, stream, items, uh, ur, ut,
                       ih, ir, itp, ph, pr, pt, oh, orr, ot, tab, relB, W2, out);
}

// Round 17
// 184.063 us; speedup vs baseline: 1.4232x; 1.4232x over previous
//
#include <hip/hip_runtime.h>

// FGKAN scoring kernel for MI355X (gfx950).
//
// Restructure: x@W1 = h_set@W1_top + path@W1_bot.
//   tab = [entB|PentB] bf16 256B rows; relB bf16 (rows 0..31 = Prel1,
//   rows 32..1055+32 = Prel2[r0*32+r1]).
//
// R15 post-mortem: k_proj_ent 128-row variant SPILLED (VGPR 256, occ 9%,
// WRITE 193MB scratch, 125us) -- rule: >=8 float4 accs/thread spills.
// k_main absent from top-5 => <125us; accounting infers ~42-48us, consistent
// with the rcp-sigmoid theory (61 -> ~45). R16: revert proj_ent to the
// R12-proven 64-row form (4 rows x float4, sW+sR LDS) + bf16 epilogue;
// k_main/k_proj_rel byte-identical to R15 (rcp-sigmoid kept) so the top-5
// finally measures k_main directly.
// R16 -> R17: identical resubmit (R16 died to GPU acquisition timeout).
//
// d_ws layout: relB (1056*64 bf16 = 132KB) | tab (NE x 128 bf16 = 25.6MB)

#define NE   100000
#define NR   32
#define DIMD 64
#define BB   4096
#define TT   32
#define BT   (BB * TT)

__device__ __forceinline__ float rcpf(float x) { return __builtin_amdgcn_rcpf(x); }
__device__ __forceinline__ float sigf(float x) {
    return rcpf(1.0f + __expf(-x));   // v_mul+v_exp+v_add+v_rcp (no IEEE div)
}
__device__ __forceinline__ float4 ld4(const float* p) {
    return *reinterpret_cast<const float4*>(p);
}

// bf16 helpers
__device__ __forceinline__ unsigned short f2b(float x) {
    unsigned b = __builtin_bit_cast(unsigned, x);
    b += 0x7FFF + ((b >> 16) & 1);
    return (unsigned short)(b >> 16);
}
__device__ __forceinline__ float blo(unsigned u) {
    return __builtin_bit_cast(float, u << 16);
}
__device__ __forceinline__ float bhi(unsigned u) {
    return __builtin_bit_cast(float, u & 0xFFFF0000u);
}
__device__ __forceinline__ void unp8(uint4 v, float* f) {
    f[0] = blo(v.x); f[1] = bhi(v.x);
    f[2] = blo(v.y); f[3] = bhi(v.y);
    f[4] = blo(v.z); f[5] = bhi(v.z);
    f[6] = blo(v.w); f[7] = bhi(v.w);
}
__device__ __forceinline__ uint4 ldu4(const unsigned* p) {
    return *reinterpret_cast<const uint4*>(p);
}

__device__ __forceinline__ float reduce8(float x) {
    x += __shfl_xor(x, 1, 64);
    x += __shfl_xor(x, 2, 64);
    x += __shfl_xor(x, 4, 64);
    return x;
}

// ---------------------------------------------------------------- precompute
// tab row r (256B) = [ entB: 64 bf16 | PentB: 64 bf16 ], Pent = ent @ W1_top.
// R12-proven: 64 rows/block, 256 threads, 4 rows x float4 per thread.
__global__ __launch_bounds__(256) void k_proj_ent(const float* __restrict__ ent,
                                                  const float* __restrict__ W1,
                                                  unsigned short* __restrict__ tab) {
    __shared__ float sW[64][68];
    __shared__ float sR[64][68];
    const int tid = threadIdx.x;
    const int row0 = blockIdx.x * 64;

#pragma unroll
    for (int i = 0; i < 4; ++i) {
        const int idx = tid + 256 * i;        // 0..1023
        const int r = idx >> 4;
        const int c = idx & 15;
        const float4 wv = ld4(W1 + r * DIMD + 4 * c);
        sW[r][4 * c + 0] = wv.x; sW[r][4 * c + 1] = wv.y;
        sW[r][4 * c + 2] = wv.z; sW[r][4 * c + 3] = wv.w;
        const int er = (row0 + r < NE) ? (row0 + r) : (NE - 1);
        const float4 rv = ld4(ent + er * DIMD + 4 * c);
        sR[r][4 * c + 0] = rv.x; sR[r][4 * c + 1] = rv.y;
        sR[r][4 * c + 2] = rv.z; sR[r][4 * c + 3] = rv.w;
    }
    __syncthreads();

    const int q = tid & 15;
    const int trow = tid >> 4;
    float4 acc0 = make_float4(0.f, 0.f, 0.f, 0.f);
    float4 acc1 = acc0, acc2 = acc0, acc3 = acc0;

#pragma unroll
    for (int kk = 0; kk < 16; ++kk) {
        const float4 r0 = ld4(&sR[4 * trow + 0][4 * kk]);
        const float4 r1 = ld4(&sR[4 * trow + 1][4 * kk]);
        const float4 r2 = ld4(&sR[4 * trow + 2][4 * kk]);
        const float4 r3 = ld4(&sR[4 * trow + 3][4 * kk]);
#pragma unroll
        for (int i = 0; i < 4; ++i) {
            const float4 wv = ld4(&sW[4 * kk + i][4 * q]);
            const float s0 = (i == 0) ? r0.x : (i == 1) ? r0.y : (i == 2) ? r0.z : r0.w;
            const float s1 = (i == 0) ? r1.x : (i == 1) ? r1.y : (i == 2) ? r1.z : r1.w;
            const float s2 = (i == 0) ? r2.x : (i == 1) ? r2.y : (i == 2) ? r2.z : r2.w;
            const float s3 = (i == 0) ? r3.x : (i == 1) ? r3.y : (i == 2) ? r3.z : r3.w;
            acc0.x = fmaf(s0, wv.x, acc0.x); acc0.y = fmaf(s0, wv.y, acc0.y);
            acc0.z = fmaf(s0, wv.z, acc0.z); acc0.w = fmaf(s0, wv.w, acc0.w);
            acc1.x = fmaf(s1, wv.x, acc1.x); acc1.y = fmaf(s1, wv.y, acc1.y);
            acc1.z = fmaf(s1, wv.z, acc1.z); acc1.w = fmaf(s1, wv.w, acc1.w);
            acc2.x = fmaf(s2, wv.x, acc2.x); acc2.y = fmaf(s2, wv.y, acc2.y);
            acc2.z = fmaf(s2, wv.z, acc2.z); acc2.w = fmaf(s2, wv.w, acc2.w);
            acc3.x = fmaf(s3, wv.x, acc3.x); acc3.y = fmaf(s3, wv.y, acc3.y);
            acc3.z = fmaf(s3, wv.z, acc3.z); acc3.w = fmaf(s3, wv.w, acc3.w);
        }
    }

    const int orow = row0 + 4 * trow;
#pragma unroll
    for (int i = 0; i < 4; ++i) {
        if (orow + i < NE) {
            const float4 a = (i == 0) ? acc0 : (i == 1) ? acc1 : (i == 2) ? acc2 : acc3;
            unsigned short* rowp = tab + ((size_t)(orow + i) << 7);
            ushort4 ev, pv;
            ev.x = f2b(sR[4 * trow + i][4 * q + 0]);
            ev.y = f2b(sR[4 * trow + i][4 * q + 1]);
            ev.z = f2b(sR[4 * trow + i][4 * q + 2]);
            ev.w = f2b(sR[4 * trow + i][4 * q + 3]);
            pv.x = f2b(a.x); pv.y = f2b(a.y); pv.z = f2b(a.z); pv.w = f2b(a.w);
            *reinterpret_cast<ushort4*>(rowp + 4 * q) = ev;
            *reinterpret_cast<ushort4*>(rowp + 64 + 4 * q) = pv;
        }
    }
}

// relB rows: [0,32) = rel[r] @ W1_bot ; [32,1056): (rel[r0]*rel[r1]) @ W1_bot
__global__ __launch_bounds__(256) void k_proj_rel(const float* __restrict__ rel,
                                                  const float* __restrict__ W1,
                                                  unsigned short* __restrict__ relB) {
    int gid = blockIdx.x * 256 + threadIdx.x;
    int row = gid >> 6;
    int d = gid & 63;
    if (row < 32) {
        const float* a = rel + row * DIMD;
        float acc = 0.0f;
#pragma unroll
        for (int k = 0; k < DIMD; ++k)
            acc = fmaf(a[k], W1[(DIMD + k) * DIMD + d], acc);
        relB[row * DIMD + d] = f2b(acc);
    } else if (row < 32 + 1024) {
        const int rr = row - 32;
        const float* a = rel + (rr >> 5) * DIMD;
        const float* c = rel + (rr & 31) * DIMD;
        float acc = 0.0f;
#pragma unroll
        for (int k = 0; k < DIMD; ++k)
            acc = fmaf(a[k] * c[k], W1[(DIMD + k) * DIMD + d], acc);
        relB[row * DIMD + d] = f2b(acc);
    }
}

// ---------------------------------------------------------------- main
// One block per b. Wave w = branch. Lane = (g = t-subgroup in [0,8),
// q = 16B dim-chunk in [0,8)). p in [0,4): t = 8p + g.
__global__ __launch_bounds__(256) void k_main(
    const int* __restrict__ items,
    const int* __restrict__ uh, const int* __restrict__ ur, const int* __restrict__ ut,
    const int* __restrict__ ih, const int* __restrict__ ir, const int* __restrict__ itp,
    const int* __restrict__ ph, const int* __restrict__ pr, const int* __restrict__ pt,
    const int* __restrict__ oh, const int* __restrict__ orr, const int* __restrict__ ot,
    const unsigned short* __restrict__ tab,
    const unsigned short* __restrict__ relB,
    const float* __restrict__ W2,
    float* __restrict__ out) {
    const int b = blockIdx.x;
    const int tid = threadIdx.x;
    const int w = tid >> 6;
    const int lane = tid & 63;
    const int g = lane >> 3;   // t-subgroup [0,8)
    const int q = lane & 7;    // dim chunk [0,8)

    const int* hp;
    const int* rp;
    const int* tp;
    switch (w) {
        case 0: hp = uh; rp = ur; tp = ut; break;
        case 1: hp = ih; rp = ir; tp = itp; break;
        case 2: hp = ph; rp = pr; tp = pt; break;
        default: hp = oh; rp = orr; tp = ot; break;
    }

    __shared__ int sidx[4][3][2][TT];
    {
        const int l = lane >> 5;
        const int t0 = lane & 31;
        const int off = l * BT + b * TT + t0;
        sidx[w][0][l][t0] = hp[off];
        sidx[w][1][l][t0] = rp[off];
        sidx[w][2][l][t0] = tp[off];
    }
    const int item_idx = (w == 1) ? items[b] : 0;

    int jh0[4], jh1[4], jr0[4], jr1[4], jt0[4], jt1[4];
#pragma unroll
    for (int p = 0; p < 4; ++p) {
        const int t = 8 * p + g;
        jh0[p] = sidx[w][0][0][t];
        jh1[p] = sidx[w][0][1][t];
        jr0[p] = sidx[w][1][0][t];
        jr1[p] = sidx[w][1][1][t];
        jt0[p] = sidx[w][2][0][t];
        jt1[p] = sidx[w][2][1][t];
    }

    const unsigned* tabU = (const unsigned*)tab;   // row = 64 uints
    const unsigned* relU = (const unsigned*)relB;  // row = 32 uints

    // ---- batched Phase-A gathers (20 dwordx4 loads)
    uint4 rH[4], rA0[4], rA1[4], rR0[4], rR2[4];
#pragma unroll
    for (int p = 0; p < 4; ++p) {
        const unsigned* r0p = tabU + ((size_t)jh0[p] << 6) + 4 * q;
        rH[p] = ldu4(r0p);
        rA0[p] = ldu4(r0p + 32);
        rA1[p] = ldu4(tabU + ((size_t)jh1[p] << 6) + 32 + 4 * q);
        rR0[p] = ldu4(relU + ((size_t)jr0[p] << 5) + 4 * q);
        rR2[p] = ldu4(relU + ((size_t)(32 + jr0[p] * 32 + jr1[p]) << 5) + 4 * q);
    }

    float w2e[8];
    {
        const float4 wa = ld4(W2 + 8 * q);
        const float4 wb = ld4(W2 + 8 * q + 4);
        w2e[0] = wa.x; w2e[1] = wa.y; w2e[2] = wa.z; w2e[3] = wa.w;
        w2e[4] = wb.x; w2e[5] = wb.y; w2e[6] = wb.z; w2e[7] = wb.w;
    }

    // ---- Phase A compute
    float d0[4], d1[4];
    float aH[8] = {0.f, 0.f, 0.f, 0.f, 0.f, 0.f, 0.f, 0.f};
#pragma unroll
    for (int p = 0; p < 4; ++p) {
        float He[8], A0e[8], A1e[8], R0e[8], R2e[8];
        unp8(rH[p], He);
        unp8(rA0[p], A0e);
        unp8(rA1[p], A1e);
        unp8(rR0[p], R0e);
        unp8(rR2[p], R2e);
        float v = 0.f, u = 0.f;
#pragma unroll
        for (int j = 0; j < 8; ++j) {
            aH[j] += He[j];
            v = fmaf(sigf(A0e[j] + R0e[j]), w2e[j], v);
            u = fmaf(sigf(A0e[j] + A1e[j] + R2e[j]), w2e[j], u);
        }
        d0[p] = v;
        d1[p] = u;
    }

    // ---- issue Phase-C gathers; latency hides under Phase B
    uint4 rT0[4], rT1[4];
#pragma unroll
    for (int p = 0; p < 4; ++p) {
        rT0[p] = ldu4(tabU + ((size_t)jt0[p] << 6) + 4 * q);
        rT1[p] = ldu4(tabU + ((size_t)jt1[p] << 6) + 4 * q);
    }
    const uint4 rIt = ldu4(tabU + ((size_t)item_idx << 6) + 4 * q);

    // ---- Phase B: 8-lane reduces; e = exp(sigmoid(dot)); deferred norm
    float e0[4], e1[4];
    float s0 = 0.f, s1 = 0.f;
#pragma unroll
    for (int p = 0; p < 4; ++p) {
        e0[p] = __expf(sigf(reduce8(d0[p])));
        e1[p] = __expf(sigf(reduce8(d1[p])));
        s0 += e0[p];
        s1 += e1[p];
    }
    s0 += __shfl_xor(s0, 8, 64);
    s0 += __shfl_xor(s0, 16, 64);
    s0 += __shfl_xor(s0, 32, 64);
    s1 += __shfl_xor(s1, 8, 64);
    s1 += __shfl_xor(s1, 16, 64);
    s1 += __shfl_xor(s1, 32, 64);

    // ---- Phase C: unnormalized weighted t-emb sums (entB halves)
    float acc0[8] = {0.f, 0.f, 0.f, 0.f, 0.f, 0.f, 0.f, 0.f};
    float acc1[8] = {0.f, 0.f, 0.f, 0.f, 0.f, 0.f, 0.f, 0.f};
#pragma unroll
    for (int p = 0; p < 4; ++p) {
        float T0e[8], T1e[8];
        unp8(rT0[p], T0e);
        unp8(rT1[p], T1e);
#pragma unroll
        for (int j = 0; j < 8; ++j) {
            acc0[j] = fmaf(e0[p], T0e[j], acc0[j]);
            acc1[j] = fmaf(e1[p], T1e[j], acc1[j]);
        }
    }

    const float inv0 = rcpf(s0);
    const float inv1 = rcpf(s1);
    float ve[8];
#pragma unroll
    for (int j = 0; j < 8; ++j) {
        ve[j] = fmaf(acc0[j], inv0, fmaf(acc1[j], inv1, 0.03125f * aH[j]));
        ve[j] += __shfl_xor(ve[j], 8, 64);
        ve[j] += __shfl_xor(ve[j], 16, 64);
        ve[j] += __shfl_xor(ve[j], 32, 64);
    }

    if (w == 1) {  // item branch additionally adds ent[items[b]] (entB half)
        float Ie[8];
        unp8(rIt, Ie);
#pragma unroll
        for (int j = 0; j < 8; ++j) ve[j] += Ie[j];
    }

    __shared__ float vec[4][DIMD];
    if (g == 0) {
#pragma unroll
        for (int j = 0; j < 8; ++j) vec[w][8 * q + j] = ve[j];
    }
    __syncthreads();

    // score = sigmoid( sum_d e_u*e_p_i + e_p_u*e_i )
    if (tid < 64) {
        float z = fmaf(vec[0][tid], vec[3][tid], vec[2][tid] * vec[1][tid]);
#pragma unroll
        for (int m = 1; m < 64; m <<= 1) z += __shfl_xor(z, m, 64);
        if (tid == 0) out[b] = sigf(z);
    }
    if (b == 0 && tid == 0) out[BB] = 0.0f;  // kge_loss
}

extern "C" void kernel_launch(void* const* d_in, const int* in_sizes, int n_in,
                              void* d_out, int out_size, void* d_ws, size_t ws_size,
                              hipStream_t stream) {
    const int* items = (const int*)d_in[0];
    const int* uh = (const int*)d_in[1];
    const int* ur = (const int*)d_in[2];
    const int* ut = (const int*)d_in[3];
    const int* ih = (const int*)d_in[4];
    const int* ir = (const int*)d_in[5];
    const int* itp = (const int*)d_in[6];
    const int* ph = (const int*)d_in[7];
    const int* pr = (const int*)d_in[8];
    const int* pt = (const int*)d_in[9];
    const int* oh = (const int*)d_in[10];
    const int* orr = (const int*)d_in[11];
    const int* ot = (const int*)d_in[12];
    const float* ent = (const float*)d_in[13];
    const float* rel = (const float*)d_in[14];
    const float* W1 = (const float*)d_in[15];
    const float* W2 = (const float*)d_in[16];
    float* out = (float*)d_out;

    unsigned short* relB = (unsigned short*)d_ws;    // 1056 rows x 64 bf16 = 132KB
    unsigned short* tab = relB + 1056 * DIMD;        // NE x 128 bf16 = 25.6MB

    hipLaunchKernelGGL(k_proj_ent, dim3((NE + 63) / 64), dim3(256), 0, stream,
                       ent, W1, tab);
    hipLaunchKernelGGL(k_proj_rel, dim3((1056 * 64 + 255) / 256), dim3(256), 0,
                       stream, rel, W1, relB);
    hipLaunchKernelGGL(k_main, dim3(BB), dim3(256), 0, stream, items, uh, ur, ut,
                       ih, ir, itp, ph, pr, pt, oh, orr, ot, tab, relB, W2, out);
}